// Round 4
// baseline (230.571 us; speedup 1.0000x reference)
//
#include <hip/hip_runtime.h>
#include <hip/hip_bf16.h>
#include <math.h>

typedef __bf16 bf16;
typedef bf16  bf16x8 __attribute__((ext_vector_type(8)));
typedef bf16  bf16x4 __attribute__((ext_vector_type(4)));
typedef float f32x4  __attribute__((ext_vector_type(4)));
typedef unsigned int u32x2 __attribute__((ext_vector_type(2)));
typedef unsigned int u32x4 __attribute__((ext_vector_type(4)));

#define B_   4
#define N_   2048
#define CH_  512
#define H_   8
#define D_   64
#define HID_ 512

__device__ __forceinline__ f32x4 mfma16(bf16x8 a, bf16x8 b, f32x4 c) {
    return __builtin_amdgcn_mfma_f32_16x16x32_bf16(a, b, c, 0, 0, 0);
}

// ---------------- rope table: cos/sin[pos][d/2], 2048 x 32 ----------------
__global__ void rope_table_k(float* __restrict__ cosT, float* __restrict__ sinT) {
    int idx = blockIdx.x * 256 + threadIdx.x;   // 65536 = 2048*32
    int pos = idx >> 5, fi = idx & 31;
    double inv = pow(10000.0, -(double)(2 * fi) / 64.0);
    double ang = (double)pos * inv;
    cosT[idx] = (float)cos(ang);
    sinT[idx] = (float)sin(ang);
}

// ---------------- QKV GEMM + scale + RoPE -> Qb/Kb/Vb bf16 [B][H][N][64] ----------------
__global__ __launch_bounds__(256) void qkv_rope_k(
    const float* __restrict__ x, const float* __restrict__ w,
    const float* __restrict__ cosT, const float* __restrict__ sinT,
    bf16* __restrict__ Qb, bf16* __restrict__ Kb, bf16* __restrict__ Vb)
{
    __shared__ __align__(16) bf16 Xs[128][40];
    __shared__ __align__(16) bf16 Ws[128][40];
    const int tid = threadIdx.x, lane = tid & 63, wid = tid >> 6;
    const int wr = wid >> 1, wc = wid & 1;
    const int m0 = blockIdx.x * 128, n0 = blockIdx.y * 128;
    const int l15 = lane & 15, l4 = lane >> 4;
    const int sr = tid >> 1, sh = (tid & 1) * 16;

    f32x4 acc[4][4] = {};

    for (int kt = 0; kt < 16; ++kt) {
        __syncthreads();
        {
            const float4* xp = reinterpret_cast<const float4*>(x + (size_t)(m0 + sr) * CH_ + kt * 32 + sh);
            const float4* wp = reinterpret_cast<const float4*>(w + (size_t)(n0 + sr) * CH_ + kt * 32 + sh);
#pragma unroll
            for (int j = 0; j < 4; ++j) {
                float4 f = xp[j];
                bf16x4 o1 = { (bf16)f.x, (bf16)f.y, (bf16)f.z, (bf16)f.w };
                *reinterpret_cast<bf16x4*>(&Xs[sr][sh + j * 4]) = o1;
                float4 g = wp[j];
                bf16x4 o2 = { (bf16)g.x, (bf16)g.y, (bf16)g.z, (bf16)g.w };
                *reinterpret_cast<bf16x4*>(&Ws[sr][sh + j * 4]) = o2;
            }
        }
        __syncthreads();
        bf16x8 a[4], bb[4];
#pragma unroll
        for (int mf = 0; mf < 4; ++mf)
            a[mf] = *reinterpret_cast<const bf16x8*>(&Xs[wr * 64 + mf * 16 + l15][l4 * 8]);
#pragma unroll
        for (int nf = 0; nf < 4; ++nf)
            bb[nf] = *reinterpret_cast<const bf16x8*>(&Ws[wc * 64 + nf * 16 + l15][l4 * 8]);
#pragma unroll
        for (int mf = 0; mf < 4; ++mf)
#pragma unroll
            for (int nf = 0; nf < 4; ++nf)
                acc[mf][nf] = mfma16(a[mf], bb[nf], acc[mf][nf]);
    }

#pragma unroll
    for (int nf = 0; nf < 4; ++nf) {
        const int col = n0 + wc * 64 + nf * 16 + l15;
        const int sec = col >> 9;            // 0=Q 1=K 2=V (uniform per block-col)
        const int cc = col & 511;
        const int hh = cc >> 6, dd = cc & 63;
        const float sgn = (dd & 1) ? 1.f : -1.f;
#pragma unroll
        for (int mf = 0; mf < 4; ++mf) {
#pragma unroll
            for (int i = 0; i < 4; ++i) {
                const int row = m0 + wr * 64 + mf * 16 + l4 * 4 + i;
                const int bb_ = row >> 11, pos = row & 2047;
                const float v = acc[mf][nf][i];
                const float v2 = __shfl_xor(v, 1);   // partner d^1
                const size_t dst = ((size_t)((bb_ * H_ + hh) * N_ + pos)) * D_ + dd;
                if (sec == 2) {
                    Vb[dst] = (bf16)v;
                } else {
                    const float c = cosT[pos * 32 + (dd >> 1)];
                    const float s = sinT[pos * 32 + (dd >> 1)];
                    const float r = v * c + sgn * v2 * s;
                    if (sec == 0) Qb[dst] = (bf16)(r * 0.125f);
                    else          Kb[dst] = (bf16)r;
                }
            }
        }
    }
}

// ---------------- flash attention v4 ----------------
// block=(qt,h,b) covering 128 q-rows, 4 waves x 32 q-rows each, KVBLK=64,
// swapped QK^T (S^T = K@Q^T), no max-tracking, dbuf LDS via global_load_lds
// (linear dest, inverse-swizzled source), V via ds_read_b64_tr_b16.
// K and V fragments are reused across the 2 q-column blocks (qb) -> LDS
// reads per MFMA halved vs v3.
#define KRD(cf,ks)  (((cf)*16 + l15)*128 + (((ks)*64 + l4*16) ^ ((l15&7)<<4)))
#define PRDQ(qb,ks) (wid*4096 + ((qb)*16 + l15)*128 + (((ks)*64 + l4*16) ^ ((l15&7)<<4)))
#define PSTQ(qb,cf) (wid*4096 + ((qb)*16 + l15)*128 + (((cf)*32 + l4*8)  ^ ((l15&7)<<4)))
#define VTR(ks,df,jj) (((ks)*32 + l4*8 + (l15>>2) + (jj)*4)*128 + \
                       ((((df)*32 + (l15&3)*8) ^ ((l15>>2)<<4)) ^ ((l4&1)<<6)))

__global__ __launch_bounds__(256, 3) void attn_k(
    const bf16* __restrict__ Qb, const bf16* __restrict__ Kb, const bf16* __restrict__ Vb,
    const float* __restrict__ bias, bf16* __restrict__ AO)
{
    __shared__ __align__(16) unsigned char KsB[2][8192];
    __shared__ __align__(16) unsigned char VsB[2][8192];
    __shared__ __align__(16) unsigned char PwB[4][4096];

    const int tid = threadIdx.x, lane = tid & 63, wid = tid >> 6;
    const int l15 = lane & 15, l4 = lane >> 4;
    const int qt = blockIdx.x, h = blockIdx.y, b = blockIdx.z;
    const int q0 = qt * 128 + wid * 32;
    const size_t bh = (size_t)(b * H_ + h) * N_ * D_;

    // Q fragments: qa[qb][ks], lane holds Q[q=q0+qb*16+l15][d=ks*32+l4*8..+8]
    bf16x8 qa[2][2];
#pragma unroll
    for (int qb = 0; qb < 2; ++qb)
#pragma unroll
        for (int ks = 0; ks < 2; ++ks)
            qa[qb][ks] = *reinterpret_cast<const bf16x8*>(
                Qb + bh + (size_t)(q0 + qb * 16 + l15) * D_ + ks * 32 + l4 * 8);

    // global_load_lds staging: linear LDS dest, swizzle folded into source col
    const unsigned kcol = ((lane & 7) * 16) ^ ((lane >> 3) << 4);
    const unsigned vcol = ((lane & 7) * 16) ^ (((lane >> 3) & 3) << 4) ^ ((wid & 1) << 6);
    const char* kg = (const char*)(Kb + bh) + (size_t)(wid * 8 + (lane >> 3)) * 128 + kcol;
    const char* vg = (const char*)(Vb + bh) + (size_t)(wid * 8 + (lane >> 3)) * 128 + vcol;

    const float* bp = bias + ((size_t)h * N_ + (q0 + l15)) * N_ + l4 * 4;

    unsigned char* pwD = &PwB[0][0];
    const unsigned vs32 = (unsigned)(size_t)&VsB[0][0];   // LDS byte address for asm tr-reads

#define GLL(src, dst) __builtin_amdgcn_global_load_lds( \
        (const __attribute__((address_space(1))) unsigned int*)(src), \
        (__attribute__((address_space(3))) unsigned int*)(dst), 16, 0, 0)

#define STAGE(buf, t) do { \
        GLL(kg + (size_t)(t) * 8192,        &KsB[buf][wid * 1024]); \
        GLL(kg + (size_t)(t) * 8192 + 4096, &KsB[buf][4096 + wid * 1024]); \
        GLL(vg + (size_t)(t) * 8192,        &VsB[buf][wid * 1024]); \
        GLL(vg + (size_t)(t) * 8192 + 4096, &VsB[buf][4096 + wid * 1024]); \
    } while (0)

    f32x4 o[2][4] = {};
    float lp[2] = { 0.f, 0.f };   // per-lane partial row-sum per qb (q = qb*16+l15)

    // ---- prologue: stage kb=0 ----
    STAGE(0, 0);
    __syncthreads();

#pragma unroll 2
    for (int kb = 0; kb < 32; ++kb) {
        const int cur = kb & 1;
        // ---- issue next-tile K/V loads first ----
        if (kb < 31) STAGE(cur ^ 1, kb + 1);

        // ---- bias loads for this iter (hidden under QK^T) ----
        f32x4 bc[2][4];
#pragma unroll
        for (int qb = 0; qb < 2; ++qb)
#pragma unroll
            for (int cf = 0; cf < 4; ++cf)
                bc[qb][cf] = *reinterpret_cast<const f32x4*>(
                    bp + (size_t)qb * 16 * N_ + kb * 64 + cf * 16);

        // ---- QK^T (swapped): S^T[k][q], K-frag shared across qb ----
        const unsigned char* ksC = &KsB[cur][0];
        f32x4 s[2][4] = {};
        __builtin_amdgcn_s_setprio(1);
#pragma unroll
        for (int cf = 0; cf < 4; ++cf) {
#pragma unroll
            for (int ks = 0; ks < 2; ++ks) {
                bf16x8 kf = *reinterpret_cast<const bf16x8*>(ksC + KRD(cf, ks));
                s[0][cf] = mfma16(kf, qa[0][ks], s[0][cf]);
                s[1][cf] = mfma16(kf, qa[1][ks], s[1][cf]);
            }
        }
        __builtin_amdgcn_s_setprio(0);

        // ---- softmax (no max subtraction): p = exp(s + bias) ----
#pragma unroll
        for (int qb = 0; qb < 2; ++qb) {
#pragma unroll
            for (int cf = 0; cf < 4; ++cf) {
                float p0 = __expf(s[qb][cf][0] + bc[qb][cf][0]);
                float p1 = __expf(s[qb][cf][1] + bc[qb][cf][1]);
                float p2 = __expf(s[qb][cf][2] + bc[qb][cf][2]);
                float p3 = __expf(s[qb][cf][3] + bc[qb][cf][3]);
                lp[qb] += (p0 + p1) + (p2 + p3);
                bf16x4 pk = { (bf16)p0, (bf16)p1, (bf16)p2, (bf16)p3 };
                *reinterpret_cast<bf16x4*>(pwD + PSTQ(qb, cf)) = pk;
            }
        }

        // ---- PV: O[q][d] += P@V ; V-frags shared across qb ----
        const unsigned vbase = vs32 + cur * 8192;
        __builtin_amdgcn_s_setprio(1);
#pragma unroll
        for (int ks = 0; ks < 2; ++ks) {
            u32x2 t0, t1, t2, t3, t4, t5, t6, t7;
            {
                unsigned a0 = vbase + VTR(ks, 0, 0), a1 = vbase + VTR(ks, 0, 1);
                unsigned a2 = vbase + VTR(ks, 1, 0), a3 = vbase + VTR(ks, 1, 1);
                unsigned a4 = vbase + VTR(ks, 2, 0), a5 = vbase + VTR(ks, 2, 1);
                unsigned a6 = vbase + VTR(ks, 3, 0), a7 = vbase + VTR(ks, 3, 1);
                asm volatile("ds_read_b64_tr_b16 %0, %1" : "=v"(t0) : "v"(a0));
                asm volatile("ds_read_b64_tr_b16 %0, %1" : "=v"(t1) : "v"(a1));
                asm volatile("ds_read_b64_tr_b16 %0, %1" : "=v"(t2) : "v"(a2));
                asm volatile("ds_read_b64_tr_b16 %0, %1" : "=v"(t3) : "v"(a3));
                asm volatile("ds_read_b64_tr_b16 %0, %1" : "=v"(t4) : "v"(a4));
                asm volatile("ds_read_b64_tr_b16 %0, %1" : "=v"(t5) : "v"(a5));
                asm volatile("ds_read_b64_tr_b16 %0, %1" : "=v"(t6) : "v"(a6));
                asm volatile("ds_read_b64_tr_b16 %0, %1" : "=v"(t7) : "v"(a7));
            }
            bf16x8 pa0 = *reinterpret_cast<const bf16x8*>(pwD + PRDQ(0, ks));
            bf16x8 pa1 = *reinterpret_cast<const bf16x8*>(pwD + PRDQ(1, ks));
            asm volatile("s_waitcnt lgkmcnt(0)" ::: "memory");
            __builtin_amdgcn_sched_barrier(0);
            {
                u32x4 w0 = { t0[0], t0[1], t1[0], t1[1] };
                bf16x8 v0 = __builtin_bit_cast(bf16x8, w0);
                o[0][0] = mfma16(pa0, v0, o[0][0]);
                o[1][0] = mfma16(pa1, v0, o[1][0]);
                u32x4 w1 = { t2[0], t2[1], t3[0], t3[1] };
                bf16x8 v1 = __builtin_bit_cast(bf16x8, w1);
                o[0][1] = mfma16(pa0, v1, o[0][1]);
                o[1][1] = mfma16(pa1, v1, o[1][1]);
                u32x4 w2 = { t4[0], t4[1], t5[0], t5[1] };
                bf16x8 v2 = __builtin_bit_cast(bf16x8, w2);
                o[0][2] = mfma16(pa0, v2, o[0][2]);
                o[1][2] = mfma16(pa1, v2, o[1][2]);
                u32x4 w3 = { t6[0], t6[1], t7[0], t7[1] };
                bf16x8 v3 = __builtin_bit_cast(bf16x8, w3);
                o[0][3] = mfma16(pa0, v3, o[0][3]);
                o[1][3] = mfma16(pa1, v3, o[1][3]);
            }
        }
        __builtin_amdgcn_s_setprio(0);

        __syncthreads();   // drains staged loads + orders LDS for next iter
    }

    // ---- epilogue: row sums -> normalize -> store ----
#pragma unroll
    for (int qb = 0; qb < 2; ++qb) {
        float tot = lp[qb];
        tot += __shfl_xor(tot, 16);
        tot += __shfl_xor(tot, 32);          // full sum for q-row qb*16 + l15
        float rinv[4];
#pragma unroll
        for (int i = 0; i < 4; ++i)
            rinv[i] = 1.0f / __shfl(tot, l4 * 4 + i);
#pragma unroll
        for (int df = 0; df < 4; ++df)
#pragma unroll
            for (int i = 0; i < 4; ++i) {
                const int row = q0 + qb * 16 + l4 * 4 + i;
                AO[((size_t)(b * N_ + row)) * HID_ + h * D_ + df * 16 + l15] =
                    (bf16)(o[qb][df][i] * rinv[i]);
            }
    }
}

// ---------------- out projection: AO(bf16) @ w_out^T -> f32 ----------------
__global__ __launch_bounds__(256) void proj_k(
    const bf16* __restrict__ A, const float* __restrict__ w, float* __restrict__ out)
{
    __shared__ __align__(16) bf16 As[128][40];
    __shared__ __align__(16) bf16 Ws[128][40];
    const int tid = threadIdx.x, lane = tid & 63, wid = tid >> 6;
    const int wr = wid >> 1, wc = wid & 1;
    const int m0 = blockIdx.x * 128, n0 = blockIdx.y * 128;
    const int l15 = lane & 15, l4 = lane >> 4;
    const int sr = tid >> 1, sh = (tid & 1) * 16;

    f32x4 acc[4][4] = {};

    for (int kt = 0; kt < 16; ++kt) {
        __syncthreads();
        {
            const bf16* ap = A + (size_t)(m0 + sr) * HID_ + kt * 32 + sh;
            *reinterpret_cast<bf16x8*>(&As[sr][sh])     = *reinterpret_cast<const bf16x8*>(ap);
            *reinterpret_cast<bf16x8*>(&As[sr][sh + 8]) = *reinterpret_cast<const bf16x8*>(ap + 8);
            const float4* wp = reinterpret_cast<const float4*>(w + (size_t)(n0 + sr) * HID_ + kt * 32 + sh);
#pragma unroll
            for (int j = 0; j < 4; ++j) {
                float4 g = wp[j];
                bf16x4 o2 = { (bf16)g.x, (bf16)g.y, (bf16)g.z, (bf16)g.w };
                *reinterpret_cast<bf16x4*>(&Ws[sr][sh + j * 4]) = o2;
            }
        }
        __syncthreads();
        bf16x8 a[4], bb[4];
#pragma unroll
        for (int mf = 0; mf < 4; ++mf)
            a[mf] = *reinterpret_cast<const bf16x8*>(&As[wr * 64 + mf * 16 + l15][l4 * 8]);
#pragma unroll
        for (int nf = 0; nf < 4; ++nf)
            bb[nf] = *reinterpret_cast<const bf16x8*>(&Ws[wc * 64 + nf * 16 + l15][l4 * 8]);
#pragma unroll
        for (int mf = 0; mf < 4; ++mf)
#pragma unroll
            for (int nf = 0; nf < 4; ++nf)
                acc[mf][nf] = mfma16(a[mf], bb[nf], acc[mf][nf]);
    }
#pragma unroll
    for (int nf = 0; nf < 4; ++nf) {
        const int col = n0 + wc * 64 + nf * 16 + l15;
#pragma unroll
        for (int mf = 0; mf < 4; ++mf) {
#pragma unroll
            for (int i = 0; i < 4; ++i) {
                const int row = m0 + wr * 64 + mf * 16 + l4 * 4 + i;
                out[(size_t)row * HID_ + col] = acc[mf][nf][i];
            }
        }
    }
}

extern "C" void kernel_launch(void* const* d_in, const int* in_sizes, int n_in,
                              void* d_out, int out_size, void* d_ws, size_t ws_size,
                              hipStream_t stream) {
    (void)in_sizes; (void)n_in; (void)out_size; (void)ws_size;
    const float* x     = (const float*)d_in[0];
    const float* bias  = (const float*)d_in[1];
    const float* w_qkv = (const float*)d_in[2];
    const float* w_out = (const float*)d_in[3];
    float* out = (float*)d_out;

    bf16* Qb = (bf16*)d_ws;                 // [4][8][2048][64]
    bf16* Kb = Qb + 4194304;
    bf16* Vb = Kb + 4194304;
    bf16* AO = Vb + 4194304;                // [4][2048][512]
    float* cosT = (float*)(AO + 4194304);   // [2048][32]
    float* sinT = cosT + 65536;

    rope_table_k<<<dim3(256), 256, 0, stream>>>(cosT, sinT);
    qkv_rope_k  <<<dim3(64, 12), 256, 0, stream>>>(x, w_qkv, cosT, sinT, Qb, Kb, Vb);
    attn_k      <<<dim3(16, 8, 4), 256, 0, stream>>>(Qb, Kb, Vb, bias, AO);
    proj_k      <<<dim3(64, 4), 256, 0, stream>>>(AO, w_out, out);
}

// Round 5
// 166.423 us; speedup vs baseline: 1.3855x; 1.3855x over previous
//
#include <hip/hip_runtime.h>
#include <hip/hip_bf16.h>
#include <math.h>

typedef __bf16 bf16;
typedef bf16  bf16x8 __attribute__((ext_vector_type(8)));
typedef bf16  bf16x4 __attribute__((ext_vector_type(4)));
typedef float f32x4  __attribute__((ext_vector_type(4)));

#define B_   4
#define N_   2048
#define CH_  512
#define H_   8
#define D_   64
#define HID_ 512

__device__ __forceinline__ f32x4 mfma16(bf16x8 a, bf16x8 b, f32x4 c) {
    return __builtin_amdgcn_mfma_f32_16x16x32_bf16(a, b, c, 0, 0, 0);
}

// ---------------- rope table: cos/sin[pos][d/2], 2048 x 32 ----------------
__global__ void rope_table_k(float* __restrict__ cosT, float* __restrict__ sinT) {
    int idx = blockIdx.x * 256 + threadIdx.x;   // 65536 = 2048*32
    int pos = idx >> 5, fi = idx & 31;
    double inv = pow(10000.0, -(double)(2 * fi) / 64.0);
    double ang = (double)pos * inv;
    cosT[idx] = (float)cos(ang);
    sinT[idx] = (float)sin(ang);
}

// ---------------- QKV GEMM + scale + RoPE -> Qb/Kb [B*H][N][64], Vt [B*H][64][N] ----------------
__global__ __launch_bounds__(256) void qkv_rope_k(
    const float* __restrict__ x, const float* __restrict__ w,
    const float* __restrict__ cosT, const float* __restrict__ sinT,
    bf16* __restrict__ Qb, bf16* __restrict__ Kb, bf16* __restrict__ Vt)
{
    __shared__ __align__(16) bf16 Xs[128][40];
    __shared__ __align__(16) bf16 Ws[128][40];
    const int tid = threadIdx.x, lane = tid & 63, wid = tid >> 6;
    const int wr = wid >> 1, wc = wid & 1;
    const int m0 = blockIdx.x * 128, n0 = blockIdx.y * 128;
    const int l15 = lane & 15, l4 = lane >> 4;
    const int sr = tid >> 1, sh = (tid & 1) * 16;

    f32x4 acc[4][4] = {};

    for (int kt = 0; kt < 16; ++kt) {
        __syncthreads();
        {
            const float4* xp = reinterpret_cast<const float4*>(x + (size_t)(m0 + sr) * CH_ + kt * 32 + sh);
            const float4* wp = reinterpret_cast<const float4*>(w + (size_t)(n0 + sr) * CH_ + kt * 32 + sh);
#pragma unroll
            for (int j = 0; j < 4; ++j) {
                float4 f = xp[j];
                bf16x4 o1 = { (bf16)f.x, (bf16)f.y, (bf16)f.z, (bf16)f.w };
                *reinterpret_cast<bf16x4*>(&Xs[sr][sh + j * 4]) = o1;
                float4 g = wp[j];
                bf16x4 o2 = { (bf16)g.x, (bf16)g.y, (bf16)g.z, (bf16)g.w };
                *reinterpret_cast<bf16x4*>(&Ws[sr][sh + j * 4]) = o2;
            }
        }
        __syncthreads();
        bf16x8 a[4], bb[4];
#pragma unroll
        for (int mf = 0; mf < 4; ++mf)
            a[mf] = *reinterpret_cast<const bf16x8*>(&Xs[wr * 64 + mf * 16 + l15][l4 * 8]);
#pragma unroll
        for (int nf = 0; nf < 4; ++nf)
            bb[nf] = *reinterpret_cast<const bf16x8*>(&Ws[wc * 64 + nf * 16 + l15][l4 * 8]);
#pragma unroll
        for (int mf = 0; mf < 4; ++mf)
#pragma unroll
            for (int nf = 0; nf < 4; ++nf)
                acc[mf][nf] = mfma16(a[mf], bb[nf], acc[mf][nf]);
    }

#pragma unroll
    for (int nf = 0; nf < 4; ++nf) {
        const int col = n0 + wc * 64 + nf * 16 + l15;
        const int sec = col >> 9;            // 0=Q 1=K 2=V (uniform per block)
        const int cc = col & 511;
        const int hh = cc >> 6, dd = cc & 63;
        if (sec == 2) {
            // V: store transposed Vt[bh][dd][pos], vectorized over i (4 consecutive pos)
#pragma unroll
            for (int mf = 0; mf < 4; ++mf) {
                const int pos0 = m0 + wr * 64 + mf * 16 + l4 * 4;
                const int bb_ = pos0 >> 11, pos = pos0 & 2047;
                bf16x4 pk = { (bf16)acc[mf][nf][0], (bf16)acc[mf][nf][1],
                              (bf16)acc[mf][nf][2], (bf16)acc[mf][nf][3] };
                *reinterpret_cast<bf16x4*>(
                    Vt + ((size_t)(bb_ * H_ + hh) * D_ + dd) * N_ + pos) = pk;
            }
        } else {
            const float sgn = (dd & 1) ? 1.f : -1.f;
#pragma unroll
            for (int mf = 0; mf < 4; ++mf) {
#pragma unroll
                for (int i = 0; i < 4; ++i) {
                    const int row = m0 + wr * 64 + mf * 16 + l4 * 4 + i;
                    const int bb_ = row >> 11, pos = row & 2047;
                    const float v = acc[mf][nf][i];
                    const float v2 = __shfl_xor(v, 1);   // partner d^1
                    const size_t dst = ((size_t)((bb_ * H_ + hh) * N_ + pos)) * D_ + dd;
                    const float c = cosT[pos * 32 + (dd >> 1)];
                    const float s = sinT[pos * 32 + (dd >> 1)];
                    const float r = v * c + sgn * v2 * s;
                    if (sec == 0) Qb[dst] = (bf16)(r * 0.125f);
                    else          Kb[dst] = (bf16)r;
                }
            }
        }
    }
}

// ---------------- flash attention v5 ----------------
// R3 skeleton: 1024 blocks (XCD-swizzled), 4 waves x 16 q-rows, KVBLK=64,
// swapped QK^T (S^T = K@Q^T), no max-tracking, bias double-buffered in regs,
// dbuf LDS via global_load_lds (linear dest, inverse-swizzled source).
// V is pre-transposed (Vt[bh][d][n]) so the PV B-frag is a plain swizzled
// ds_read_b128 -- no tr-reads, no hard lgkmcnt(0) stalls.
#define KRD(r16,ks) (((r16)*16 + l15)*128 + (((ks)*64 + l4*16) ^ ((l15&7)<<4)))
#define PRD(ks)     (wid*2048 + l15*128 + (((ks)*64 + l4*16) ^ ((l15&7)<<4)))
#define PST(cf)     (wid*2048 + l15*128 + (((cf)*32 + l4*8)  ^ ((l15&7)<<4)))

__global__ __launch_bounds__(256, 4) void attn_k(
    const bf16* __restrict__ Qb, const bf16* __restrict__ Kb, const bf16* __restrict__ Vt,
    const float* __restrict__ bias, bf16* __restrict__ AO)
{
    __shared__ __align__(16) unsigned char KsB[2][8192];
    __shared__ __align__(16) unsigned char VsB[2][8192];
    __shared__ __align__(16) unsigned char PwB[4][2048];

    const int tid = threadIdx.x, lane = tid & 63, wid = tid >> 6;
    const int l15 = lane & 15, l4 = lane >> 4;
    // XCD swizzle: blocks with id%8==x all run on XCD x and sweep one (b,h)
    // at a time -> K/Vt tile (1 MB) stays resident in that XCD's L2.
    const int id = blockIdx.x;
    const int xcd = id & 7, j = id >> 3;
    const int bh = xcd + 8 * (j >> 5);
    const int qt = j & 31;
    const int b = bh >> 3, h = bh & 7;
    const int q0 = qt * 64 + wid * 16;
    const size_t bhoff = (size_t)bh * N_ * D_;

    // Q fragments (B-operand of swapped QK^T): lane holds Q[q=l15][d=ks*32+l4*8..+8]
    bf16x8 qa[2];
#pragma unroll
    for (int ks = 0; ks < 2; ++ks)
        qa[ks] = *reinterpret_cast<const bf16x8*>(Qb + bhoff + (size_t)(q0 + l15) * D_ + ks * 32 + l4 * 8);

    // global_load_lds staging: linear LDS dest, swizzle folded into source col
    const unsigned kcol = ((lane & 7) * 16) ^ ((lane >> 3) << 4);
    const char* kg = (const char*)(Kb + bhoff) + (size_t)(wid * 8 + (lane >> 3)) * 128 + kcol;
    const char* vg = (const char*)(Vt + bhoff) + (size_t)(wid * 8 + (lane >> 3)) * (N_ * 2) + kcol;

    const float* bp = bias + ((size_t)h * N_ + (q0 + l15)) * N_ + l4 * 4;

    unsigned char* pwD = &PwB[0][0];

#define GLL(src, dst) __builtin_amdgcn_global_load_lds( \
        (const __attribute__((address_space(1))) unsigned int*)(src), \
        (__attribute__((address_space(3))) unsigned int*)(dst), 16, 0, 0)

#define STAGE(buf, t) do { \
        GLL(kg + (size_t)(t) * 8192,          &KsB[buf][wid * 1024]); \
        GLL(kg + (size_t)(t) * 8192 + 4096,   &KsB[buf][4096 + wid * 1024]); \
        GLL(vg + (size_t)(t) * 128,           &VsB[buf][wid * 1024]); \
        GLL(vg + (size_t)(t) * 128 + 131072,  &VsB[buf][4096 + wid * 1024]); \
    } while (0)

    f32x4 o[4] = {};
    float lp = 0.f;     // per-lane partial row-sum (q = l15)
    f32x4 bc[4], bn[4];

    // ---- prologue: stage kb=0, load bias(kb=0) ----
    STAGE(0, 0);
#pragma unroll
    for (int cf = 0; cf < 4; ++cf)
        bc[cf] = *reinterpret_cast<const f32x4*>(bp + cf * 16);
    __syncthreads();

#pragma unroll 2
    for (int kb = 0; kb < 32; ++kb) {
        const int cur = kb & 1;
        // ---- issue next-tile loads first: latency hides under this iter ----
        if (kb < 31) {
            STAGE(cur ^ 1, kb + 1);
#pragma unroll
            for (int cf = 0; cf < 4; ++cf)
                bn[cf] = *reinterpret_cast<const f32x4*>(bp + (size_t)(kb + 1) * 64 + cf * 16);
        }

        // ---- QK^T (swapped): S^T[k][q], A = K-frag, B = Q-frag ----
        const unsigned char* ksC = &KsB[cur][0];
        f32x4 s[4] = {};
        __builtin_amdgcn_s_setprio(1);
#pragma unroll
        for (int cf = 0; cf < 4; ++cf) {
#pragma unroll
            for (int ks = 0; ks < 2; ++ks) {
                bf16x8 kf = *reinterpret_cast<const bf16x8*>(ksC + KRD(cf, ks));
                s[cf] = mfma16(kf, qa[ks], s[cf]);
            }
        }
        __builtin_amdgcn_s_setprio(0);

        // ---- softmax (no max subtraction): p = exp(s + bias) ----
#pragma unroll
        for (int cf = 0; cf < 4; ++cf) {
            float p0 = __expf(s[cf][0] + bc[cf][0]);
            float p1 = __expf(s[cf][1] + bc[cf][1]);
            float p2 = __expf(s[cf][2] + bc[cf][2]);
            float p3 = __expf(s[cf][3] + bc[cf][3]);
            lp += (p0 + p1) + (p2 + p3);
            bf16x4 pk = { (bf16)p0, (bf16)p1, (bf16)p2, (bf16)p3 };
            *reinterpret_cast<bf16x4*>(pwD + PST(cf)) = pk;   // P[q=l15][k=16cf+4*l4+0..3]
        }

        // ---- PV: O[q][d] += P@V ; V-frags are plain swizzled b128 reads ----
        const unsigned char* vsC = &VsB[cur][0];
        __builtin_amdgcn_s_setprio(1);
#pragma unroll
        for (int ks = 0; ks < 2; ++ks) {
            bf16x8 pa = *reinterpret_cast<const bf16x8*>(pwD + PRD(ks));
#pragma unroll
            for (int df = 0; df < 4; ++df) {
                bf16x8 vf = *reinterpret_cast<const bf16x8*>(vsC + KRD(df, ks));
                o[df] = mfma16(pa, vf, o[df]);
            }
        }
        __builtin_amdgcn_s_setprio(0);

#pragma unroll
        for (int cf = 0; cf < 4; ++cf) bc[cf] = bn[cf];
        __syncthreads();   // drains staged loads + orders LDS for next iter
    }

    // ---- epilogue: row sums -> normalize -> store ----
    float tot = lp;
    tot += __shfl_xor(tot, 16);
    tot += __shfl_xor(tot, 32);          // full sum for q = l15 (all l4 copies)
    float rinv[4];
#pragma unroll
    for (int i = 0; i < 4; ++i)
        rinv[i] = 1.0f / __shfl(tot, l4 * 4 + i);   // sum for q-row l4*4+i

#pragma unroll
    for (int df = 0; df < 4; ++df)
#pragma unroll
        for (int i = 0; i < 4; ++i) {
            const int row = q0 + l4 * 4 + i;
            AO[((size_t)(b * N_ + row)) * HID_ + h * D_ + df * 16 + l15] = (bf16)(o[df][i] * rinv[i]);
        }
}

// ---------------- out projection: AO(bf16) @ w_out^T -> f32 ----------------
__global__ __launch_bounds__(256) void proj_k(
    const bf16* __restrict__ A, const float* __restrict__ w, float* __restrict__ out)
{
    __shared__ __align__(16) bf16 As[128][40];
    __shared__ __align__(16) bf16 Ws[128][40];
    const int tid = threadIdx.x, lane = tid & 63, wid = tid >> 6;
    const int wr = wid >> 1, wc = wid & 1;
    const int m0 = blockIdx.x * 128, n0 = blockIdx.y * 128;
    const int l15 = lane & 15, l4 = lane >> 4;
    const int sr = tid >> 1, sh = (tid & 1) * 16;

    f32x4 acc[4][4] = {};

    for (int kt = 0; kt < 16; ++kt) {
        __syncthreads();
        {
            const bf16* ap = A + (size_t)(m0 + sr) * HID_ + kt * 32 + sh;
            *reinterpret_cast<bf16x8*>(&As[sr][sh])     = *reinterpret_cast<const bf16x8*>(ap);
            *reinterpret_cast<bf16x8*>(&As[sr][sh + 8]) = *reinterpret_cast<const bf16x8*>(ap + 8);
            const float4* wp = reinterpret_cast<const float4*>(w + (size_t)(n0 + sr) * HID_ + kt * 32 + sh);
#pragma unroll
            for (int j = 0; j < 4; ++j) {
                float4 g = wp[j];
                bf16x4 o2 = { (bf16)g.x, (bf16)g.y, (bf16)g.z, (bf16)g.w };
                *reinterpret_cast<bf16x4*>(&Ws[sr][sh + j * 4]) = o2;
            }
        }
        __syncthreads();
        bf16x8 a[4], bb[4];
#pragma unroll
        for (int mf = 0; mf < 4; ++mf)
            a[mf] = *reinterpret_cast<const bf16x8*>(&As[wr * 64 + mf * 16 + l15][l4 * 8]);
#pragma unroll
        for (int nf = 0; nf < 4; ++nf)
            bb[nf] = *reinterpret_cast<const bf16x8*>(&Ws[wc * 64 + nf * 16 + l15][l4 * 8]);
#pragma unroll
        for (int mf = 0; mf < 4; ++mf)
#pragma unroll
            for (int nf = 0; nf < 4; ++nf)
                acc[mf][nf] = mfma16(a[mf], bb[nf], acc[mf][nf]);
    }
#pragma unroll
    for (int nf = 0; nf < 4; ++nf) {
        const int col = n0 + wc * 64 + nf * 16 + l15;
#pragma unroll
        for (int mf = 0; mf < 4; ++mf) {
#pragma unroll
            for (int i = 0; i < 4; ++i) {
                const int row = m0 + wr * 64 + mf * 16 + l4 * 4 + i;
                out[(size_t)row * HID_ + col] = acc[mf][nf][i];
            }
        }
    }
}

extern "C" void kernel_launch(void* const* d_in, const int* in_sizes, int n_in,
                              void* d_out, int out_size, void* d_ws, size_t ws_size,
                              hipStream_t stream) {
    (void)in_sizes; (void)n_in; (void)out_size; (void)ws_size;
    const float* x     = (const float*)d_in[0];
    const float* bias  = (const float*)d_in[1];
    const float* w_qkv = (const float*)d_in[2];
    const float* w_out = (const float*)d_in[3];
    float* out = (float*)d_out;

    bf16* Qb = (bf16*)d_ws;                 // [4*8][2048][64]
    bf16* Kb = Qb + 4194304;                // [4*8][2048][64]
    bf16* Vt = Kb + 4194304;                // [4*8][64][2048] (transposed)
    bf16* AO = Vt + 4194304;                // [4][2048][512]
    float* cosT = (float*)(AO + 4194304);   // [2048][32]
    float* sinT = cosT + 65536;

    rope_table_k<<<dim3(256), 256, 0, stream>>>(cosT, sinT);
    qkv_rope_k  <<<dim3(64, 12), 256, 0, stream>>>(x, w_qkv, cosT, sinT, Qb, Kb, Vt);
    attn_k      <<<dim3(1024), 256, 0, stream>>>(Qb, Kb, Vt, bias, AO);
    proj_k      <<<dim3(64, 4), 256, 0, stream>>>(AO, w_out, out);
}

// Round 6
// 154.234 us; speedup vs baseline: 1.4949x; 1.0790x over previous
//
#include <hip/hip_runtime.h>
#include <hip/hip_bf16.h>
#include <math.h>

typedef __bf16 bf16;
typedef bf16  bf16x8 __attribute__((ext_vector_type(8)));
typedef bf16  bf16x4 __attribute__((ext_vector_type(4)));
typedef float f32x4  __attribute__((ext_vector_type(4)));
typedef float f32x16 __attribute__((ext_vector_type(16)));

#define B_   4
#define N_   2048
#define CH_  512
#define H_   8
#define D_   64
#define HID_ 512

__device__ __forceinline__ f32x4 mfma16(bf16x8 a, bf16x8 b, f32x4 c) {
    return __builtin_amdgcn_mfma_f32_16x16x32_bf16(a, b, c, 0, 0, 0);
}
__device__ __forceinline__ f32x16 mfma32(bf16x8 a, bf16x8 b, f32x16 c) {
    return __builtin_amdgcn_mfma_f32_32x32x16_bf16(a, b, c, 0, 0, 0);
}

// ---------------- rope table: cos/sin[pos][d/2], 2048 x 32 ----------------
__global__ void rope_table_k(float* __restrict__ cosT, float* __restrict__ sinT) {
    int idx = blockIdx.x * 256 + threadIdx.x;   // 65536 = 2048*32
    int pos = idx >> 5, fi = idx & 31;
    double inv = pow(10000.0, -(double)(2 * fi) / 64.0);
    double ang = (double)pos * inv;
    cosT[idx] = (float)cos(ang);
    sinT[idx] = (float)sin(ang);
}

// ---------------- QKV GEMM + scale + RoPE -> Qb/Kb [B*H][N][64], Vt [B*H][64][N] ----------------
__global__ __launch_bounds__(256) void qkv_rope_k(
    const float* __restrict__ x, const float* __restrict__ w,
    const float* __restrict__ cosT, const float* __restrict__ sinT,
    bf16* __restrict__ Qb, bf16* __restrict__ Kb, bf16* __restrict__ Vt)
{
    __shared__ __align__(16) bf16 Xs[128][40];
    __shared__ __align__(16) bf16 Ws[128][40];
    const int tid = threadIdx.x, lane = tid & 63, wid = tid >> 6;
    const int wr = wid >> 1, wc = wid & 1;
    const int m0 = blockIdx.x * 128, n0 = blockIdx.y * 128;
    const int l15 = lane & 15, l4 = lane >> 4;
    const int sr = tid >> 1, sh = (tid & 1) * 16;

    f32x4 acc[4][4] = {};

    for (int kt = 0; kt < 16; ++kt) {
        __syncthreads();
        {
            const float4* xp = reinterpret_cast<const float4*>(x + (size_t)(m0 + sr) * CH_ + kt * 32 + sh);
            const float4* wp = reinterpret_cast<const float4*>(w + (size_t)(n0 + sr) * CH_ + kt * 32 + sh);
#pragma unroll
            for (int j = 0; j < 4; ++j) {
                float4 f = xp[j];
                bf16x4 o1 = { (bf16)f.x, (bf16)f.y, (bf16)f.z, (bf16)f.w };
                *reinterpret_cast<bf16x4*>(&Xs[sr][sh + j * 4]) = o1;
                float4 g = wp[j];
                bf16x4 o2 = { (bf16)g.x, (bf16)g.y, (bf16)g.z, (bf16)g.w };
                *reinterpret_cast<bf16x4*>(&Ws[sr][sh + j * 4]) = o2;
            }
        }
        __syncthreads();
        bf16x8 a[4], bb[4];
#pragma unroll
        for (int mf = 0; mf < 4; ++mf)
            a[mf] = *reinterpret_cast<const bf16x8*>(&Xs[wr * 64 + mf * 16 + l15][l4 * 8]);
#pragma unroll
        for (int nf = 0; nf < 4; ++nf)
            bb[nf] = *reinterpret_cast<const bf16x8*>(&Ws[wc * 64 + nf * 16 + l15][l4 * 8]);
#pragma unroll
        for (int mf = 0; mf < 4; ++mf)
#pragma unroll
            for (int nf = 0; nf < 4; ++nf)
                acc[mf][nf] = mfma16(a[mf], bb[nf], acc[mf][nf]);
    }

#pragma unroll
    for (int nf = 0; nf < 4; ++nf) {
        const int col = n0 + wc * 64 + nf * 16 + l15;
        const int sec = col >> 9;            // 0=Q 1=K 2=V (uniform per block)
        const int cc = col & 511;
        const int hh = cc >> 6, dd = cc & 63;
        if (sec == 2) {
            // V: store transposed Vt[bh][dd][pos], vectorized over i (4 consecutive pos)
#pragma unroll
            for (int mf = 0; mf < 4; ++mf) {
                const int pos0 = m0 + wr * 64 + mf * 16 + l4 * 4;
                const int bb_ = pos0 >> 11, pos = pos0 & 2047;
                bf16x4 pk = { (bf16)acc[mf][nf][0], (bf16)acc[mf][nf][1],
                              (bf16)acc[mf][nf][2], (bf16)acc[mf][nf][3] };
                *reinterpret_cast<bf16x4*>(
                    Vt + ((size_t)(bb_ * H_ + hh) * D_ + dd) * N_ + pos) = pk;
            }
        } else {
            const float sgn = (dd & 1) ? 1.f : -1.f;
#pragma unroll
            for (int mf = 0; mf < 4; ++mf) {
#pragma unroll
                for (int i = 0; i < 4; ++i) {
                    const int row = m0 + wr * 64 + mf * 16 + l4 * 4 + i;
                    const int bb_ = row >> 11, pos = row & 2047;
                    const float v = acc[mf][nf][i];
                    const float v2 = __shfl_xor(v, 1);   // partner d^1
                    const size_t dst = ((size_t)((bb_ * H_ + hh) * N_ + pos)) * D_ + dd;
                    const float c = cosT[pos * 32 + (dd >> 1)];
                    const float s = sinT[pos * 32 + (dd >> 1)];
                    const float r = v * c + sgn * v2 * s;
                    if (sec == 0) Qb[dst] = (bf16)(r * 0.125f);
                    else          Kb[dst] = (bf16)r;
                }
            }
        }
    }
}

// ---------------- flash attention v6: 32x32 MFMA ----------------
// 1024 blocks (XCD-swizzled), 2 waves x 32 q-rows, KVBLK=64.
// Swapped QK^T (S^T = K@Q^T) with mfma_f32_32x32x16_bf16; no max-tracking;
// bias double-buffered in regs; dbuf K/V LDS via global_load_lds (linear
// dest, inverse-swizzled source); V pre-transposed in global (Vt[bh][d][n]).
// Frag layouts (32x32x16): A[row=l&31][k=(l>>5)*8+j]; B[k=(l>>5)*8+j][col=l&31];
// C col=l&31, row=(reg&3)+8*(reg>>2)+4*(l>>5).
#define KRD2(kt2,kc) (((kt2)*32 + l31)*128 + (((kc)*32 + l5*16) ^ (l7<<4)))
#define VRD2(dt,kt)  (((dt)*32 + l31)*128 + (((kt)*32 + l5*16) ^ (l7<<4)))
#define PRD2(kt)     (wid*4096 + l31*128 + (((kt)*32 + l5*16) ^ (l7<<4)))
#define PST2(kt2,r2) (wid*4096 + l31*128 + (((kt2)*64 + (r2)*16 + l5*8) ^ (l7<<4)))

__global__ __launch_bounds__(128, 2) void attn_k(
    const bf16* __restrict__ Qb, const bf16* __restrict__ Kb, const bf16* __restrict__ Vt,
    const float* __restrict__ bias, bf16* __restrict__ AO)
{
    __shared__ __align__(16) unsigned char KsB[2][8192];
    __shared__ __align__(16) unsigned char VsB[2][8192];
    __shared__ __align__(16) unsigned char PwB[2][4096];

    const int tid = threadIdx.x, lane = tid & 63, wid = tid >> 6;
    const int l31 = lane & 31, l5 = lane >> 5, l7 = lane & 7;
    // XCD swizzle: each XCD sweeps 4 bh values, 32 qt-blocks each -> K/Vt
    // of the active bh (~512 KB) stays L2-resident.
    const int id = blockIdx.x;
    const int xcd = id & 7, j = id >> 3;
    const int bh = xcd + 8 * (j >> 5);
    const int qt = j & 31;
    const int b = bh >> 3, h = bh & 7;
    const int q0 = qt * 64 + wid * 32;
    const size_t bhoff = (size_t)bh * N_ * D_;

    // Q in regs: qreg[kc] = Q[q0+l31][kc*16 + l5*8 ..+8]  (B-operand of QK^T)
    bf16x8 qreg[4];
#pragma unroll
    for (int kc = 0; kc < 4; ++kc)
        qreg[kc] = *reinterpret_cast<const bf16x8*>(
            Qb + bhoff + (size_t)(q0 + l31) * D_ + kc * 16 + l5 * 8);

    // global_load_lds staging: linear LDS dest, swizzle folded into source col
    const unsigned scol = ((lane & 7) * 16) ^ ((lane >> 3) << 4);
    const char* kg = (const char*)(Kb + bhoff) + (size_t)(wid * 32 + (lane >> 3)) * 128 + scol;
    const char* vg = (const char*)(Vt + bhoff) + (size_t)(wid * 32 + (lane >> 3)) * (N_ * 2) + scol;

    const float* bp = bias + ((size_t)h * N_ + (q0 + l31)) * N_ + l5 * 4;

    unsigned char* pwD = &PwB[0][0];

#define GLL(src, dst) __builtin_amdgcn_global_load_lds( \
        (const __attribute__((address_space(1))) unsigned int*)(src), \
        (__attribute__((address_space(3))) unsigned int*)(dst), 16, 0, 0)

#define STAGE(buf, t) do { \
        GLL(kg + (size_t)(t) * 8192,            &KsB[buf][wid * 4096]); \
        GLL(kg + (size_t)(t) * 8192 + 1024,     &KsB[buf][wid * 4096 + 1024]); \
        GLL(kg + (size_t)(t) * 8192 + 2048,     &KsB[buf][wid * 4096 + 2048]); \
        GLL(kg + (size_t)(t) * 8192 + 3072,     &KsB[buf][wid * 4096 + 3072]); \
        GLL(vg + (size_t)(t) * 128,             &VsB[buf][wid * 4096]); \
        GLL(vg + (size_t)(t) * 128 + 32768,     &VsB[buf][wid * 4096 + 1024]); \
        GLL(vg + (size_t)(t) * 128 + 65536,     &VsB[buf][wid * 4096 + 2048]); \
        GLL(vg + (size_t)(t) * 128 + 98304,     &VsB[buf][wid * 4096 + 3072]); \
    } while (0)

    f32x16 o[2] = {};
    float lp = 0.f;     // per-lane partial column-sum for q = l31 (over this lane's k-rows)
    f32x4 bc[2][4], bn[2][4];

    // ---- prologue: stage kb=0, load bias(kb=0) ----
    STAGE(0, 0);
#pragma unroll
    for (int kt2 = 0; kt2 < 2; ++kt2)
#pragma unroll
        for (int r2 = 0; r2 < 4; ++r2)
            bc[kt2][r2] = *reinterpret_cast<const f32x4*>(bp + kt2 * 32 + r2 * 8);
    __syncthreads();

#pragma unroll 2
    for (int kb = 0; kb < 32; ++kb) {
        const int cur = kb & 1;
        // ---- issue next-tile loads first: latency hides under this iter ----
        if (kb < 31) {
            STAGE(cur ^ 1, kb + 1);
#pragma unroll
            for (int kt2 = 0; kt2 < 2; ++kt2)
#pragma unroll
                for (int r2 = 0; r2 < 4; ++r2)
                    bn[kt2][r2] = *reinterpret_cast<const f32x4*>(
                        bp + (size_t)(kb + 1) * 64 + kt2 * 32 + r2 * 8);
        }

        // ---- QK^T (swapped): S^T[k=64][q=32], A = K-frag, B = Q-regs ----
        const unsigned char* ksC = &KsB[cur][0];
        f32x16 s[2] = {};
        __builtin_amdgcn_s_setprio(1);
#pragma unroll
        for (int kt2 = 0; kt2 < 2; ++kt2) {
#pragma unroll
            for (int kc = 0; kc < 4; ++kc) {
                bf16x8 kf = *reinterpret_cast<const bf16x8*>(ksC + KRD2(kt2, kc));
                s[kt2] = mfma32(kf, qreg[kc], s[kt2]);
            }
        }
        __builtin_amdgcn_s_setprio(0);

        // ---- softmax (no max subtraction): p = exp(s + bias), pack to LDS ----
#pragma unroll
        for (int kt2 = 0; kt2 < 2; ++kt2) {
#pragma unroll
            for (int r2 = 0; r2 < 4; ++r2) {
                float p0 = __expf(s[kt2][r2 * 4 + 0] + bc[kt2][r2][0]);
                float p1 = __expf(s[kt2][r2 * 4 + 1] + bc[kt2][r2][1]);
                float p2 = __expf(s[kt2][r2 * 4 + 2] + bc[kt2][r2][2]);
                float p3 = __expf(s[kt2][r2 * 4 + 3] + bc[kt2][r2][3]);
                lp += (p0 + p1) + (p2 + p3);
                bf16x4 pk = { (bf16)p0, (bf16)p1, (bf16)p2, (bf16)p3 };
                *reinterpret_cast<bf16x4*>(pwD + PST2(kt2, r2)) = pk;
            }
        }

        // ---- PV: O[q=32][d=64] += P@V ; A = P-frag, B = Vt-frag ----
        const unsigned char* vsC = &VsB[cur][0];
        __builtin_amdgcn_s_setprio(1);
#pragma unroll
        for (int kt = 0; kt < 4; ++kt) {
            bf16x8 pa = *reinterpret_cast<const bf16x8*>(pwD + PRD2(kt));
#pragma unroll
            for (int dt = 0; dt < 2; ++dt) {
                bf16x8 vf = *reinterpret_cast<const bf16x8*>(vsC + VRD2(dt, kt));
                o[dt] = mfma32(pa, vf, o[dt]);
            }
        }
        __builtin_amdgcn_s_setprio(0);

#pragma unroll
        for (int kt2 = 0; kt2 < 2; ++kt2)
#pragma unroll
            for (int r2 = 0; r2 < 4; ++r2)
                bc[kt2][r2] = bn[kt2][r2];
        __syncthreads();   // drains staged loads + orders LDS for next iter
    }

    // ---- epilogue: column sums -> normalize -> store ----
    float tot = lp;
    tot += __shfl_xor(tot, 32);          // full softmax denom for q = l31
    float rv[16];
#pragma unroll
    for (int reg = 0; reg < 16; ++reg) {
        const int qr = (reg & 3) + 8 * (reg >> 2) + 4 * l5;
        rv[reg] = 1.0f / __shfl(tot, qr);
    }
#pragma unroll
    for (int dt = 0; dt < 2; ++dt)
#pragma unroll
        for (int reg = 0; reg < 16; ++reg) {
            const int qr = (reg & 3) + 8 * (reg >> 2) + 4 * l5;
            AO[((size_t)(b * N_ + q0 + qr)) * HID_ + h * D_ + dt * 32 + l31] =
                (bf16)(o[dt][reg] * rv[reg]);
        }
}

// ---------------- out projection: AO(bf16) @ w_out^T -> f32 ----------------
__global__ __launch_bounds__(256) void proj_k(
    const bf16* __restrict__ A, const float* __restrict__ w, float* __restrict__ out)
{
    __shared__ __align__(16) bf16 As[128][40];
    __shared__ __align__(16) bf16 Ws[128][40];
    const int tid = threadIdx.x, lane = tid & 63, wid = tid >> 6;
    const int wr = wid >> 1, wc = wid & 1;
    const int m0 = blockIdx.x * 128, n0 = blockIdx.y * 128;
    const int l15 = lane & 15, l4 = lane >> 4;
    const int sr = tid >> 1, sh = (tid & 1) * 16;

    f32x4 acc[4][4] = {};

    for (int kt = 0; kt < 16; ++kt) {
        __syncthreads();
        {
            const bf16* ap = A + (size_t)(m0 + sr) * HID_ + kt * 32 + sh;
            *reinterpret_cast<bf16x8*>(&As[sr][sh])     = *reinterpret_cast<const bf16x8*>(ap);
            *reinterpret_cast<bf16x8*>(&As[sr][sh + 8]) = *reinterpret_cast<const bf16x8*>(ap + 8);
            const float4* wp = reinterpret_cast<const float4*>(w + (size_t)(n0 + sr) * HID_ + kt * 32 + sh);
#pragma unroll
            for (int j = 0; j < 4; ++j) {
                float4 g = wp[j];
                bf16x4 o2 = { (bf16)g.x, (bf16)g.y, (bf16)g.z, (bf16)g.w };
                *reinterpret_cast<bf16x4*>(&Ws[sr][sh + j * 4]) = o2;
            }
        }
        __syncthreads();
        bf16x8 a[4], bb[4];
#pragma unroll
        for (int mf = 0; mf < 4; ++mf)
            a[mf] = *reinterpret_cast<const bf16x8*>(&As[wr * 64 + mf * 16 + l15][l4 * 8]);
#pragma unroll
        for (int nf = 0; nf < 4; ++nf)
            bb[nf] = *reinterpret_cast<const bf16x8*>(&Ws[wc * 64 + nf * 16 + l15][l4 * 8]);
#pragma unroll
        for (int mf = 0; mf < 4; ++mf)
#pragma unroll
            for (int nf = 0; nf < 4; ++nf)
                acc[mf][nf] = mfma16(a[mf], bb[nf], acc[mf][nf]);
    }
#pragma unroll
    for (int nf = 0; nf < 4; ++nf) {
        const int col = n0 + wc * 64 + nf * 16 + l15;
#pragma unroll
        for (int mf = 0; mf < 4; ++mf) {
#pragma unroll
            for (int i = 0; i < 4; ++i) {
                const int row = m0 + wr * 64 + mf * 16 + l4 * 4 + i;
                out[(size_t)row * HID_ + col] = acc[mf][nf][i];
            }
        }
    }
}

extern "C" void kernel_launch(void* const* d_in, const int* in_sizes, int n_in,
                              void* d_out, int out_size, void* d_ws, size_t ws_size,
                              hipStream_t stream) {
    (void)in_sizes; (void)n_in; (void)out_size; (void)ws_size;
    const float* x     = (const float*)d_in[0];
    const float* bias  = (const float*)d_in[1];
    const float* w_qkv = (const float*)d_in[2];
    const float* w_out = (const float*)d_in[3];
    float* out = (float*)d_out;

    bf16* Qb = (bf16*)d_ws;                 // [4*8][2048][64]
    bf16* Kb = Qb + 4194304;                // [4*8][2048][64]
    bf16* Vt = Kb + 4194304;                // [4*8][64][2048] (transposed)
    bf16* AO = Vt + 4194304;                // [4][2048][512]
    float* cosT = (float*)(AO + 4194304);   // [2048][32]
    float* sinT = cosT + 65536;

    rope_table_k<<<dim3(256), 256, 0, stream>>>(cosT, sinT);
    qkv_rope_k  <<<dim3(64, 12), 256, 0, stream>>>(x, w_qkv, cosT, sinT, Qb, Kb, Vt);
    attn_k      <<<dim3(1024), 128, 0, stream>>>(Qb, Kb, Vt, bias, AO);
    proj_k      <<<dim3(64, 4), 256, 0, stream>>>(AO, w_out, out);
}